// Round 5
// baseline (1493.126 us; speedup 1.0000x reference)
//
#include <hip/hip_runtime.h>
#include <hip/hip_bf16.h>

// Sizes: T=256, B=2048, NC=3, NM=125, IN=128, H=256, 4H=1024, K_gates=384
// 512 WGs x 256 thr, EXACTLY 2 WGs/CU (LDS pad + launch_bounds). WG = (s,r):
//   s = h-col slice 0..7 (32 h-cols), r = row block 0..63 (rows [32r, 32r+32)).
// blockIdx = r*8+s so the two WGs sharing a CU are in DIFFERENT exchange groups:
// while one WG waits in its h-exchange poll/barrier, the sibling's MFMA/VALU
// phases fill the SIMDs (TLP latency hiding; no intra-WG role coupling).
// TRANSPOSED GEMMs (32x32x16), all weights persistent in VGPR/AGPR A-frags.
// Per step: ONLY h exchanged among the 8 slice-WGs of a row block (sc0/sc1
// coherent accesses + one relaxed agent-scope flag barrier, parity dbuf).
constexpr int TSTEPS = 255;
constexpr int XROW   = 392;   // LDS x|h row stride (shorts): [x 0..127 | h 128..383] + 8 pad

typedef __attribute__((ext_vector_type(8))) short short8;
typedef __attribute__((ext_vector_type(4))) float f32x4;
typedef __attribute__((ext_vector_type(16))) float f32x16;
typedef __attribute__((ext_vector_type(4))) int i32x4;
typedef __attribute__((ext_vector_type(2))) unsigned int u32x2;

__device__ __forceinline__ unsigned short f2bf(float f) {
    __hip_bfloat16 h = __float2bfloat16(f);
    return *reinterpret_cast<unsigned short*>(&h);
}
__device__ __forceinline__ float bf2f(unsigned short u) {
    __hip_bfloat16 h;
    *reinterpret_cast<unsigned short*>(&h) = u;
    return __bfloat162float(h);
}
__device__ __forceinline__ float sigf(float x) {
    return __builtin_amdgcn_rcpf(1.f + __expf(-x));
}
__device__ __forceinline__ float tanh_fast(float x) {
    x = fminf(fmaxf(x, -15.f), 15.f);
    float e = __expf(-2.f * x);
    return (1.f - e) * __builtin_amdgcn_rcpf(1.f + e);
}

// Coherent (cross-XCD) accesses: sc0 sc1 bypass non-coherent caches.
__device__ __forceinline__ i32x4 load_coh16(const void* p) {
    i32x4 r;
    asm volatile("global_load_dwordx4 %0, %1, off sc0 sc1" : "=v"(r) : "v"(p) : "memory");
    return r;
}
__device__ __forceinline__ void store_coh16(void* p, i32x4 v) {
    asm volatile("global_store_dwordx4 %0, %1, off sc0 sc1" :: "v"(p), "v"(v) : "memory");
}

// 8-WG group barrier: vmcnt drain (covers inline-asm coherent stores) -> syncthreads
// -> leader relaxed agent-scope add + poll -> syncthreads. While the leader polls,
// this WG's other waves are parked at s_barrier -> sibling WG owns the SIMDs.
__device__ __forceinline__ void groupbar(unsigned int* cnt, unsigned int tgt, int tid) {
    asm volatile("s_waitcnt vmcnt(0)" ::: "memory");
    __syncthreads();
    if (tid == 0) {
        __hip_atomic_fetch_add(cnt, 1u, __ATOMIC_RELAXED, __HIP_MEMORY_SCOPE_AGENT);
        while (__hip_atomic_load(cnt, __ATOMIC_RELAXED, __HIP_MEMORY_SCOPE_AGENT) < tgt)
            __builtin_amdgcn_s_sleep(1);
    }
    __syncthreads();
}

// ---------------------------------------------------------------------------
// Prep: pack weights to bf16 MFMA A-fragment order; fuse biases; zero flags.
// Gate pack (393216, 32x32x16 A-frags): idx = (((s*4+gm)*24+kt)*64+l)*8+j
//   pm = l&31; n = (pm&3)*256 + s*32 + gm*8 + (pm>>2); k = kt*16 + (l>>5)*8 + j
// Out pack (32768, 32x32x16 A-frags): idx = ((om*16+kt)*64+l)*8+j
//   oc = om*32 + (l&31); k = kt*16 + (l>>5)*8 + j
// ---------------------------------------------------------------------------
__global__ void prep_kernel(const float* __restrict__ Wih, const float* __restrict__ Whh,
                            const float* __restrict__ bih, const float* __restrict__ bhh,
                            const float* __restrict__ Wcat, const float* __restrict__ bcat,
                            const float* __restrict__ Wval, const float* __restrict__ bval,
                            unsigned short* __restrict__ Wg, unsigned short* __restrict__ Wo,
                            float* __restrict__ bg, float* __restrict__ bo,
                            unsigned int* __restrict__ flags) {
    int idx = blockIdx.x * 256 + threadIdx.x;
    if (idx < 393216) {
        int j   = idx & 7;
        int l   = (idx >> 3) & 63;
        int t24 = idx >> 9;
        int kt  = t24 % 24;
        int u   = t24 / 24;            // s*4 + gm
        int gm = u & 3, ss = u >> 2;
        int pm = l & 31;
        int n  = (pm & 3) * 256 + ss * 32 + gm * 8 + (pm >> 2);
        int k  = kt * 16 + (l >> 5) * 8 + j;
        float v = (k < 128) ? Wih[n * 128 + k] : Whh[n * 256 + (k - 128)];
        Wg[idx] = f2bf(v);
    } else if (idx < 425984) {
        int i2 = idx - 393216;
        int j = i2 & 7, ll = (i2 >> 3) & 63, kt = (i2 >> 9) & 15, om = i2 >> 13;
        int n = om * 32 + (ll & 31);
        int k = kt * 16 + (ll >> 5) * 8 + j;
        float v = (n < 3) ? Wcat[n * 256 + k] : Wval[(n - 3) * 256 + k];
        Wo[i2] = f2bf(v);
    } else if (idx < 427008) {
        int i3 = idx - 425984;
        bg[i3] = bih[i3] + bhh[i3];
    } else if (idx < 427136) {
        int i4 = idx - 427008;
        bo[i4] = (i4 < 3) ? bcat[i4] : bval[i4 - 3];
    } else if (idx < 428160) {
        flags[idx - 427136] = 0u;      // barrier counters (re-zeroed every launch/replay)
    }
}

// ---------------------------------------------------------------------------
// Main persistent kernel: grid=512, 256 threads, exactly 2 WGs/CU.
// ---------------------------------------------------------------------------
__global__ __launch_bounds__(256, 2) void rnn_kernel(
    const float* __restrict__ seq,
    const unsigned short* __restrict__ Wg, const unsigned short* __restrict__ Wo,
    const float* __restrict__ bg, const float* __restrict__ bo,
    unsigned short* __restrict__ hb, unsigned int* __restrict__ flags,
    float* __restrict__ out) {

    __shared__ __align__(16) unsigned short xh[32][XROW];   // 25088 B: [x(128)|h(256)] per row
    __shared__ __align__(16) float bgl[128];                // permuted gate bias
    __shared__ __align__(16) float obl[128];                // permuted out bias
    extern __shared__ char lds_pad[];                       // +53248 B -> 79.4 KB -> 2 WG/CU
    (void)lds_pad;

    const int tid = threadIdx.x;
    const int wv  = tid >> 6, l = tid & 63;                 // wv 0..3
    const int c   = l & 31, lh = l >> 5;
    const int s   = blockIdx.x & 7;        // col slice 0..7
    const int r   = blockIdx.x >> 3;       // row block 0..63  (sibling WGs: r differs)
    const int row0 = r * 32;
    const int hm  = wv;                    // m-tile within role (gate col tile / out col tile)
    const bool hm0lh0 = (hm == 0) && (lh == 0);

    unsigned int* cnt = flags + r * 16;    // 64B-spaced counter per group

    // ---- persistent weight A-fragments in VGPR/AGPR ----
    short8 wga[24], woa[16];
    {
        const short8* WgV = reinterpret_cast<const short8*>(Wg);
        const short8* WoV = reinterpret_cast<const short8*>(Wo);
#pragma unroll
        for (int kt = 0; kt < 24; ++kt) wga[kt] = WgV[(size_t)(((s * 4 + hm) * 24 + kt) * 64) + l];
#pragma unroll
        for (int kt = 0; kt < 16; ++kt) woa[kt] = WoV[(size_t)((hm * 16 + kt) * 64) + l];
    }

    // ---- permuted biases -> LDS ----
    if (tid < 128) {
        int gm_ = tid >> 5, lh_ = (tid >> 4) & 1, i_ = tid & 15;
        int pm = (i_ & 3) + 8 * (i_ >> 2) + 4 * lh_;
        bgl[tid] = bg[(pm & 3) * 256 + s * 32 + gm_ * 8 + (pm >> 2)];
        obl[tid] = bo[gm_ * 32 + 8 * (i_ >> 2) + 4 * lh_ + (i_ & 3)];
    }

    // ---- x(0) = bf16(seq[0]) (NaN-free), h(0) = 0 ----
#pragma unroll
    for (int i = 0; i < 4; ++i) {
        int ch = i * 256 + tid;            // 1024 float4 chunks = 32 rows x 128 cols
        int row = ch >> 5, c4 = ch & 31;
        f32x4 v = *reinterpret_cast<const f32x4*>(seq + (size_t)(row0 + row) * 128 + c4 * 4);
        unsigned short* p = &xh[row][c4 * 4];
        p[0] = f2bf(v[0]); p[1] = f2bf(v[1]); p[2] = f2bf(v[2]); p[3] = f2bf(v[3]);
    }
    {
        short8 z = {0, 0, 0, 0, 0, 0, 0, 0};
#pragma unroll
        for (int i = 0; i < 4; ++i) {
            int ch = i * 256 + tid;        // 1024 short8 chunks = 32 rows x 256 h-cols
            *reinterpret_cast<short8*>(&xh[ch >> 5][128 + (ch & 31) * 8]) = z;
        }
    }

    // ---- reg-resident bf16 x(t) at lane's 16 cols (row c, base hm*32+4lh) ----
    unsigned int xv[8];
    {
        const float* sp0 = seq + (size_t)(row0 + c) * 128 + hm * 32 + 4 * lh;
#pragma unroll
        for (int g = 0; g < 4; ++g) {
            f32x4 v = *reinterpret_cast<const f32x4*>(sp0 + 8 * g);
            xv[2 * g]     = (unsigned)f2bf(v[0]) | ((unsigned)f2bf(v[1]) << 16);
            xv[2 * g + 1] = (unsigned)f2bf(v[2]) | ((unsigned)f2bf(v[3]) << 16);
        }
    }

    float cst[4] = {0.f, 0.f, 0.f, 0.f};
    const float* bgp = &bgl[(hm * 2 + lh) * 16];
    const float* obp = &obl[(hm * 2 + lh) * 16];
    const unsigned short* xrow = &xh[c][0];

    __syncthreads();

    for (int t = 0; t < TSTEPS; ++t) {
        // ---- prefetch seq[t+1] (consumed after the barrier) ----
        f32x4 sq[4];
        if (t < TSTEPS - 1) {
            const float* sp = seq + ((size_t)(t + 1) * 2048 + row0 + c) * 128 + hm * 32 + 4 * lh;
#pragma unroll
            for (int g = 0; g < 4; ++g) sq[g] = *reinterpret_cast<const f32x4*>(sp + 8 * g);
        }

        // ---- A: gates^T = Wg.[x|h]^T + b  (24 MFMA / wave, 2-way acc chain) ----
        f32x16 acc, accB;
#pragma unroll
        for (int i = 0; i < 16; ++i) { acc[i] = bgp[i]; accB[i] = 0.f; }
        __builtin_amdgcn_s_setprio(1);
#pragma unroll
        for (int kt = 0; kt < 24; kt += 2) {
            short8 b0 = *reinterpret_cast<const short8*>(xrow + kt * 16 + lh * 8);
            short8 b1 = *reinterpret_cast<const short8*>(xrow + (kt + 1) * 16 + lh * 8);
            acc  = __builtin_amdgcn_mfma_f32_32x32x16_bf16(wga[kt], b0, acc, 0, 0, 0);
            accB = __builtin_amdgcn_mfma_f32_32x32x16_bf16(wga[kt + 1], b1, accB, 0, 0, 0);
        }
        __builtin_amdgcn_s_setprio(0);
#pragma unroll
        for (int i = 0; i < 16; ++i) acc[i] += accB[i];

        // ---- B: LSTM (in-lane); pack pairs across lh; coherent h-slice store ----
        float hn[4];
#pragma unroll
        for (int g = 0; g < 4; ++g) {
            float cn = sigf(acc[4 * g + 1]) * cst[g] + sigf(acc[4 * g]) * tanh_fast(acc[4 * g + 2]);
            hn[g] = sigf(acc[4 * g + 3]) * tanh_fast(cn);
            cst[g] = cn;
        }
        {
            i32x4 hw;
#pragma unroll
            for (int g = 0; g < 4; ++g) {
                float other = __shfl_xor(hn[g], 32);
                unsigned short lo = f2bf(lh ? other : hn[g]);
                unsigned short hi = f2bf(lh ? hn[g] : other);
                hw[g] = (int)((unsigned)lo | ((unsigned)hi << 16));
            }
            if (lh == 0) {
                char* hp = (char*)hb + (size_t)(t & 1) * 1048576 + (size_t)r * 16384
                         + (size_t)c * 512 + s * 64 + hm * 16;
                store_coh16(hp, hw);
            }
        }

        groupbar(cnt, 8u * (t + 1), tid);      // all 8 slices published h(t+1)

        // ---- restage full h(t+1) row-block: coherent 16B loads -> LDS ----
        {
            const unsigned short* hsrc = hb + (size_t)(t & 1) * 524288 + (size_t)r * 8192;
            i32x4 hv[4];
#pragma unroll
            for (int i = 0; i < 4; ++i) {
                int ch = i * 256 + tid;        // 1024 chunks: row = ch>>5, seg = ch&31
                hv[i] = load_coh16(hsrc + (size_t)((ch >> 5) * 256 + (ch & 31) * 8));
            }
            asm volatile("s_waitcnt vmcnt(0)" ::: "memory");
            __builtin_amdgcn_sched_barrier(0);
#pragma unroll
            for (int i = 0; i < 4; ++i) {
                int ch = i * 256 + tid;
                *reinterpret_cast<i32x4*>(&xh[ch >> 5][128 + (ch & 31) * 8]) = hv[i];
            }
        }
        __syncthreads();

        // ---- C: out^T = Wo.h^T + b  (16 MFMA / wave, 2-way acc chain) ----
        f32x16 acc2, acc2B;
#pragma unroll
        for (int i = 0; i < 16; ++i) { acc2[i] = obp[i]; acc2B[i] = 0.f; }
        __builtin_amdgcn_s_setprio(1);
#pragma unroll
        for (int kt = 0; kt < 16; kt += 2) {
            short8 b0 = *reinterpret_cast<const short8*>(xrow + 128 + kt * 16 + lh * 8);
            short8 b1 = *reinterpret_cast<const short8*>(xrow + 128 + (kt + 1) * 16 + lh * 8);
            acc2  = __builtin_amdgcn_mfma_f32_32x32x16_bf16(woa[kt], b0, acc2, 0, 0, 0);
            acc2B = __builtin_amdgcn_mfma_f32_32x32x16_bf16(woa[kt + 1], b1, acc2B, 0, 0, 0);
        }
        __builtin_amdgcn_s_setprio(0);

        // ---- D: + i_val (reg-resident), in-lane softmax over cols 0..2 ----
        float vv[16];
#pragma unroll
        for (int g = 0; g < 4; ++g) {
#pragma unroll
            for (int j = 0; j < 4; ++j) {
                int i = 4 * g + j;
                float v = acc2[i] + acc2B[i];
                unsigned short x16 = (unsigned short)(xv[2 * g + (j >> 1)] >> ((j & 1) * 16));
                bool isCat = (g == 0) && (j < 3) && hm0lh0;
                if (!isCat) v += bf2f(x16);
                vv[i] = v;
            }
        }
        if (hm0lh0) {
            float mx = fmaxf(fmaxf(vv[0], vv[1]), vv[2]);
            float e0 = __expf(vv[0] - mx), e1 = __expf(vv[1] - mx), e2 = __expf(vv[2] - mx);
            float rs = __builtin_amdgcn_rcpf(e0 + e1 + e2);
            vv[0] = e0 * rs; vv[1] = e1 * rs; vv[2] = e2 * rs;
        }

        // ---- E: store own 16-col out slice; impute x(t+1) locally into LDS+regs ----
        if (hm == (s >> 1)) {
            int gp = (s & 1) * 2;
            size_t ob0 = ((size_t)t * 2048 + row0 + c) * 128 + hm * 32 + 4 * lh;
            f32x4 o0 = {vv[4 * gp], vv[4 * gp + 1], vv[4 * gp + 2], vv[4 * gp + 3]};
            f32x4 o1 = {vv[4 * gp + 4], vv[4 * gp + 5], vv[4 * gp + 6], vv[4 * gp + 7]};
            *reinterpret_cast<f32x4*>(out + ob0 + 8 * gp) = o0;
            *reinterpret_cast<f32x4*>(out + ob0 + 8 * gp + 8) = o1;
        }
        if (t < TSTEPS - 1) {
#pragma unroll
            for (int g = 0; g < 4; ++g) {
                unsigned int w0 = 0, w1 = 0;
#pragma unroll
                for (int j = 0; j < 4; ++j) {
                    float sqv = sq[g][j];
                    float xf = (sqv != sqv) ? vv[4 * g + j] : sqv;   // isnan -> model output
                    unsigned short nv = f2bf(xf);
                    if (j < 2) w0 |= (unsigned)nv << (16 * j);
                    else       w1 |= (unsigned)nv << (16 * (j - 2));
                }
                xv[2 * g] = w0; xv[2 * g + 1] = w1;
                u32x2 wp = {w0, w1};
                *reinterpret_cast<u32x2*>(&xh[c][hm * 32 + 8 * g + 4 * lh]) = wp;
            }
        }
        __syncthreads();
    }
}

// ---------------------------------------------------------------------------
extern "C" void kernel_launch(void* const* d_in, const int* in_sizes, int n_in,
                              void* d_out, int out_size, void* d_ws, size_t ws_size,
                              hipStream_t stream) {
    const float* seq  = (const float*)d_in[0];
    const float* Wih  = (const float*)d_in[1];
    const float* Whh  = (const float*)d_in[2];
    const float* bih  = (const float*)d_in[3];
    const float* bhh  = (const float*)d_in[4];
    const float* Wcat = (const float*)d_in[5];
    const float* bcat = (const float*)d_in[6];
    const float* Wval = (const float*)d_in[7];
    const float* bval = (const float*)d_in[8];

    char* ws = (char*)d_ws;
    unsigned short* Wg    = (unsigned short*)(ws);                 //  786432 B
    unsigned short* Wo    = (unsigned short*)(ws + 786432);        //   65536 B
    float*          bgp   = (float*)(ws + 851968);                 //    4096 B
    float*          bop   = (float*)(ws + 856064);                 //     512 B
    unsigned int*   flags = (unsigned int*)(ws + 856576);          //    4096 B
    unsigned short* hbuf  = (unsigned short*)(ws + 860672);        // 2097152 B (2 parity buffers)
    // total ws use: 2957824 B

    prep_kernel<<<1673, 256, 0, stream>>>(Wih, Whh, bih, bhh, Wcat, bcat, Wval, bval,
                                          Wg, Wo, bgp, bop, flags);
    rnn_kernel<<<512, 256, 53248, stream>>>(seq, Wg, Wo, bgp, bop, hbuf, flags, (float*)d_out);
}

// Round 6
// 1436.147 us; speedup vs baseline: 1.0397x; 1.0397x over previous
//
#include <hip/hip_runtime.h>
#include <hip/hip_bf16.h>

// Sizes: T=256, B=2048, NC=3, NM=125, IN=128, H=256, 4H=1024, K_gates=384
// 256 WGs x 512 thr, 1 WG/CU (LDS pad). bid = s*32 + rbase  (s = h-col slice 0..7,
// rbase = 0..31), so bid%8 = rbase%8 -> a group's 8 slice-WGs share an XCD (L2
// locality for seq + h-exchange; this was round 3's accidental win, now explicit).
// DUAL-PIPELINE WG: half H0 (waves 0-3) runs row-group rbase (rows [32*rbase,+32)),
// half H1 (waves 4-7) runs row-group rbase+32. Halves are fully independent:
// intra-half sync = LDS-atomic 4-wave generation barriers (NO WG __syncthreads in
// the loop), each half has its own group flag + hb region. Wave i and i+4 share a
// SIMD -> while one half polls the LLC flag / waits on the exchange, the sibling
// half's MFMA/VALU fills the SIMD (TLP hiding with zero placement assumptions).
// Per-half body = round-5's verified 4-wave pipeline (transposed GEMMs, weights
// persistent in VGPR A-frags, sc0/sc1 coherent h exchange, parity dbuf).
constexpr int TSTEPS = 255;
constexpr int XROW   = 392;   // LDS x|h row stride (shorts): [x 0..127 | h 128..383] + 8 pad

typedef __attribute__((ext_vector_type(8))) short short8;
typedef __attribute__((ext_vector_type(4))) float f32x4;
typedef __attribute__((ext_vector_type(16))) float f32x16;
typedef __attribute__((ext_vector_type(4))) int i32x4;
typedef __attribute__((ext_vector_type(2))) unsigned int u32x2;

__device__ __forceinline__ unsigned short f2bf(float f) {
    __hip_bfloat16 h = __float2bfloat16(f);
    return *reinterpret_cast<unsigned short*>(&h);
}
__device__ __forceinline__ float bf2f(unsigned short u) {
    __hip_bfloat16 h;
    *reinterpret_cast<unsigned short*>(&h) = u;
    return __bfloat162float(h);
}
__device__ __forceinline__ float sigf(float x) {
    return __builtin_amdgcn_rcpf(1.f + __expf(-x));
}
__device__ __forceinline__ float tanh_fast(float x) {
    x = fminf(fmaxf(x, -15.f), 15.f);
    float e = __expf(-2.f * x);
    return (1.f - e) * __builtin_amdgcn_rcpf(1.f + e);
}

// Coherent (cross-XCD) accesses: sc0 sc1 bypass non-coherent caches.
__device__ __forceinline__ i32x4 load_coh16(const void* p) {
    i32x4 r;
    asm volatile("global_load_dwordx4 %0, %1, off sc0 sc1" : "=v"(r) : "v"(p) : "memory");
    return r;
}
__device__ __forceinline__ void store_coh16(void* p, i32x4 v) {
    asm volatile("global_store_dwordx4 %0, %1, off sc0 sc1" :: "v"(p), "v"(v) : "memory");
}

// ---------------------------------------------------------------------------
// Prep: pack weights to bf16 MFMA A-fragment order; fuse biases; zero flags.
// Gate pack (393216, 32x32x16 A-frags): idx = (((s*4+gm)*24+kt)*64+l)*8+j
//   pm = l&31; n = (pm&3)*256 + s*32 + gm*8 + (pm>>2); k = kt*16 + (l>>5)*8 + j
// Out pack (32768, 32x32x16 A-frags): idx = ((om*16+kt)*64+l)*8+j
//   oc = om*32 + (l&31); k = kt*16 + (l>>5)*8 + j
// ---------------------------------------------------------------------------
__global__ void prep_kernel(const float* __restrict__ Wih, const float* __restrict__ Whh,
                            const float* __restrict__ bih, const float* __restrict__ bhh,
                            const float* __restrict__ Wcat, const float* __restrict__ bcat,
                            const float* __restrict__ Wval, const float* __restrict__ bval,
                            unsigned short* __restrict__ Wg, unsigned short* __restrict__ Wo,
                            float* __restrict__ bg, float* __restrict__ bo,
                            unsigned int* __restrict__ flags) {
    int idx = blockIdx.x * 256 + threadIdx.x;
    if (idx < 393216) {
        int j   = idx & 7;
        int l   = (idx >> 3) & 63;
        int t24 = idx >> 9;
        int kt  = t24 % 24;
        int u   = t24 / 24;            // s*4 + gm
        int gm = u & 3, ss = u >> 2;
        int pm = l & 31;
        int n  = (pm & 3) * 256 + ss * 32 + gm * 8 + (pm >> 2);
        int k  = kt * 16 + (l >> 5) * 8 + j;
        float v = (k < 128) ? Wih[n * 128 + k] : Whh[n * 256 + (k - 128)];
        Wg[idx] = f2bf(v);
    } else if (idx < 425984) {
        int i2 = idx - 393216;
        int j = i2 & 7, ll = (i2 >> 3) & 63, kt = (i2 >> 9) & 15, om = i2 >> 13;
        int n = om * 32 + (ll & 31);
        int k = kt * 16 + (ll >> 5) * 8 + j;
        float v = (n < 3) ? Wcat[n * 256 + k] : Wval[(n - 3) * 256 + k];
        Wo[i2] = f2bf(v);
    } else if (idx < 427008) {
        int i3 = idx - 425984;
        bg[i3] = bih[i3] + bhh[i3];
    } else if (idx < 427136) {
        int i4 = idx - 427008;
        bo[i4] = (i4 < 3) ? bcat[i4] : bval[i4 - 3];
    } else if (idx < 428160) {
        flags[idx - 427136] = 0u;      // barrier counters (re-zeroed every launch/replay)
    }
}

// ---------------------------------------------------------------------------
// Main persistent kernel: grid=256, 512 threads, 1 WG/CU (84 KB LDS).
// ---------------------------------------------------------------------------
__global__ __launch_bounds__(512, 2) void rnn_kernel(
    const float* __restrict__ seq,
    const unsigned short* __restrict__ Wg, const unsigned short* __restrict__ Wo,
    const float* __restrict__ bg, const float* __restrict__ bo,
    unsigned short* __restrict__ hb, unsigned int* __restrict__ flags,
    float* __restrict__ out) {

    __shared__ __align__(16) unsigned short xh[2][32][XROW];  // 50176 B: per-half [x|h]
    __shared__ __align__(16) float bgl[128];                  // permuted gate bias
    __shared__ __align__(16) float obl[128];                  // permuted out bias
    __shared__ unsigned int lbar[2][32];                      // per-half barrier ctr, 128B apart
    extern __shared__ char lds_pad[];                         // +32768 B -> ~84 KB -> 1 WG/CU
    (void)lds_pad;

    const int tid  = threadIdx.x;
    const int ht   = tid >> 8;             // half 0/1
    const int ltid = tid & 255;            // thread id within half
    const int wv   = ltid >> 6;            // wave within half 0..3
    const int l    = tid & 63;
    const int c    = l & 31, lh = l >> 5;
    const int s     = blockIdx.x >> 5;     // col slice 0..7
    const int rbase = blockIdx.x & 31;
    const int gid   = rbase + (ht << 5);   // row group 0..63 (H1: +32, same %8 -> same XCD)
    const int row0  = gid * 32;
    const int hm   = wv;                   // m-tile within role
    const bool hm0lh0 = (hm == 0) && (lh == 0);

    unsigned int* cnt = flags + gid * 16;  // 64B-spaced global flag per group
    unsigned int* lb  = &lbar[ht][0];
    if (ltid == 0) lbar[ht][0] = 0u;

    // ---- persistent weight A-fragments in VGPRs ----
    short8 wga[24], woa[16];
    {
        const short8* WgV = reinterpret_cast<const short8*>(Wg);
        const short8* WoV = reinterpret_cast<const short8*>(Wo);
#pragma unroll
        for (int kt = 0; kt < 24; ++kt) wga[kt] = WgV[(size_t)(((s * 4 + hm) * 24 + kt) * 64) + l];
#pragma unroll
        for (int kt = 0; kt < 16; ++kt) woa[kt] = WoV[(size_t)((hm * 16 + kt) * 64) + l];
    }

    // ---- permuted biases -> LDS (same content for both halves) ----
    if (tid < 128) {
        int gm_ = tid >> 5, lh_ = (tid >> 4) & 1, i_ = tid & 15;
        int pm = (i_ & 3) + 8 * (i_ >> 2) + 4 * lh_;
        bgl[tid] = bg[(pm & 3) * 256 + s * 32 + gm_ * 8 + (pm >> 2)];
        obl[tid] = bo[gm_ * 32 + 8 * (i_ >> 2) + 4 * lh_ + (i_ & 3)];
    }

    // ---- x(0) = bf16(seq[0]) (NaN-free), h(0) = 0  (per half) ----
#pragma unroll
    for (int i = 0; i < 4; ++i) {
        int ch = i * 256 + ltid;           // 1024 float4 chunks = 32 rows x 128 cols
        int row = ch >> 5, c4 = ch & 31;
        f32x4 v = *reinterpret_cast<const f32x4*>(seq + (size_t)(row0 + row) * 128 + c4 * 4);
        unsigned short* p = &xh[ht][row][c4 * 4];
        p[0] = f2bf(v[0]); p[1] = f2bf(v[1]); p[2] = f2bf(v[2]); p[3] = f2bf(v[3]);
    }
    {
        short8 z = {0, 0, 0, 0, 0, 0, 0, 0};
#pragma unroll
        for (int i = 0; i < 4; ++i) {
            int ch = i * 256 + ltid;       // 1024 short8 chunks = 32 rows x 256 h-cols
            *reinterpret_cast<short8*>(&xh[ht][ch >> 5][128 + (ch & 31) * 8]) = z;
        }
    }

    // ---- reg-resident bf16 x(t) at lane's 16 cols (row c, base hm*32+4lh) ----
    unsigned int xv[8];
    {
        const float* sp0 = seq + (size_t)(row0 + c) * 128 + hm * 32 + 4 * lh;
#pragma unroll
        for (int g = 0; g < 4; ++g) {
            f32x4 v = *reinterpret_cast<const f32x4*>(sp0 + 8 * g);
            xv[2 * g]     = (unsigned)f2bf(v[0]) | ((unsigned)f2bf(v[1]) << 16);
            xv[2 * g + 1] = (unsigned)f2bf(v[2]) | ((unsigned)f2bf(v[3]) << 16);
        }
    }

    float cst[4] = {0.f, 0.f, 0.f, 0.f};
    const float* bgp = &bgl[(hm * 2 + lh) * 16];
    const float* obp = &obl[(hm * 2 + lh) * 16];
    const unsigned short* xrow = &xh[ht][c][0];

    __syncthreads();   // ONCE: biases + lbar init visible. No WG-wide sync after this.

    // 4-wave half-barrier: generation-counted LDS atomic (no coupling across halves)
    unsigned int bgen = 0;
#define HBAR() do {                                                                   \
        ++bgen;                                                                       \
        asm volatile("s_waitcnt lgkmcnt(0)" ::: "memory");                            \
        __builtin_amdgcn_sched_barrier(0);                                            \
        if (l == 0)                                                                   \
            __hip_atomic_fetch_add(lb, 1u, __ATOMIC_RELAXED, __HIP_MEMORY_SCOPE_WORKGROUP); \
        while (__hip_atomic_load(lb, __ATOMIC_RELAXED, __HIP_MEMORY_SCOPE_WORKGROUP)  \
               < 4u * bgen)                                                           \
            __builtin_amdgcn_s_sleep(1);                                              \
        __builtin_amdgcn_sched_barrier(0);                                            \
    } while (0)

    for (int t = 0; t < TSTEPS; ++t) {
        // ---- prefetch seq[t+1] (consumed after the exchange) ----
        f32x4 sq[4];
        if (t < TSTEPS - 1) {
            const float* sp = seq + ((size_t)(t + 1) * 2048 + row0 + c) * 128 + hm * 32 + 4 * lh;
#pragma unroll
            for (int g = 0; g < 4; ++g) sq[g] = *reinterpret_cast<const f32x4*>(sp + 8 * g);
        }

        // ---- A: gates^T = Wg.[x|h]^T + b  (24 MFMA / wave, 2-way acc chain) ----
        f32x16 acc, accB;
#pragma unroll
        for (int i = 0; i < 16; ++i) { acc[i] = bgp[i]; accB[i] = 0.f; }
        __builtin_amdgcn_s_setprio(1);
#pragma unroll
        for (int kt = 0; kt < 24; kt += 2) {
            short8 b0 = *reinterpret_cast<const short8*>(xrow + kt * 16 + lh * 8);
            short8 b1 = *reinterpret_cast<const short8*>(xrow + (kt + 1) * 16 + lh * 8);
            acc  = __builtin_amdgcn_mfma_f32_32x32x16_bf16(wga[kt], b0, acc, 0, 0, 0);
            accB = __builtin_amdgcn_mfma_f32_32x32x16_bf16(wga[kt + 1], b1, accB, 0, 0, 0);
        }
        __builtin_amdgcn_s_setprio(0);
#pragma unroll
        for (int i = 0; i < 16; ++i) acc[i] += accB[i];

        // ---- B: LSTM (in-lane); pack pairs across lh; coherent h-slice store ----
        float hn[4];
#pragma unroll
        for (int g = 0; g < 4; ++g) {
            float cn = sigf(acc[4 * g + 1]) * cst[g] + sigf(acc[4 * g]) * tanh_fast(acc[4 * g + 2]);
            hn[g] = sigf(acc[4 * g + 3]) * tanh_fast(cn);
            cst[g] = cn;
        }
        {
            i32x4 hw;
#pragma unroll
            for (int g = 0; g < 4; ++g) {
                float other = __shfl_xor(hn[g], 32);
                unsigned short lo = f2bf(lh ? other : hn[g]);
                unsigned short hi = f2bf(lh ? hn[g] : other);
                hw[g] = (int)((unsigned)lo | ((unsigned)hi << 16));
            }
            if (lh == 0) {
                char* hp = (char*)hb + (size_t)(t & 1) * 1048576 + (size_t)gid * 16384
                         + (size_t)c * 512 + s * 64 + hm * 16;
                store_coh16(hp, hw);
            }
        }

        // ---- group flag barrier (half-local; leader polls while sibling computes) ----
        asm volatile("s_waitcnt vmcnt(0)" ::: "memory");
        HBAR();                                // all 4 waves' coherent stores drained
        if (ltid == 0) {
            __hip_atomic_fetch_add(cnt, 1u, __ATOMIC_RELAXED, __HIP_MEMORY_SCOPE_AGENT);
            while (__hip_atomic_load(cnt, __ATOMIC_RELAXED, __HIP_MEMORY_SCOPE_AGENT)
                   < 8u * (unsigned)(t + 1))
                __builtin_amdgcn_s_sleep(1);
        }
        HBAR();                                // leader's poll complete -> h(t+1) at LLC

        // ---- restage full h(t+1) row-block: coherent 16B loads -> LDS ----
        {
            const unsigned short* hsrc = hb + (size_t)(t & 1) * 524288 + (size_t)gid * 8192;
            i32x4 hv[4];
#pragma unroll
            for (int i = 0; i < 4; ++i) {
                int ch = i * 256 + ltid;       // 1024 chunks: row = ch>>5, seg = ch&31
                hv[i] = load_coh16(hsrc + (size_t)((ch >> 5) * 256 + (ch & 31) * 8));
            }
            asm volatile("s_waitcnt vmcnt(0)" ::: "memory");
            __builtin_amdgcn_sched_barrier(0);
#pragma unroll
            for (int i = 0; i < 4; ++i) {
                int ch = i * 256 + ltid;
                *reinterpret_cast<i32x4*>(&xh[ht][ch >> 5][128 + (ch & 31) * 8]) = hv[i];
            }
        }
        HBAR();                                // restage visible to the half's 4 waves

        // ---- C: out^T = Wo.h^T + b  (16 MFMA / wave, 2-way acc chain) ----
        f32x16 acc2, acc2B;
#pragma unroll
        for (int i = 0; i < 16; ++i) { acc2[i] = obp[i]; acc2B[i] = 0.f; }
        __builtin_amdgcn_s_setprio(1);
#pragma unroll
        for (int kt = 0; kt < 16; kt += 2) {
            short8 b0 = *reinterpret_cast<const short8*>(xrow + 128 + kt * 16 + lh * 8);
            short8 b1 = *reinterpret_cast<const short8*>(xrow + 128 + (kt + 1) * 16 + lh * 8);
            acc2  = __builtin_amdgcn_mfma_f32_32x32x16_bf16(woa[kt], b0, acc2, 0, 0, 0);
            acc2B = __builtin_amdgcn_mfma_f32_32x32x16_bf16(woa[kt + 1], b1, acc2B, 0, 0, 0);
        }
        __builtin_amdgcn_s_setprio(0);

        // ---- D: + i_val (reg-resident), in-lane softmax over cols 0..2 ----
        float vv[16];
#pragma unroll
        for (int g = 0; g < 4; ++g) {
#pragma unroll
            for (int j = 0; j < 4; ++j) {
                int i = 4 * g + j;
                float v = acc2[i] + acc2B[i];
                unsigned short x16 = (unsigned short)(xv[2 * g + (j >> 1)] >> ((j & 1) * 16));
                bool isCat = (g == 0) && (j < 3) && hm0lh0;
                if (!isCat) v += bf2f(x16);
                vv[i] = v;
            }
        }
        if (hm0lh0) {
            float mx = fmaxf(fmaxf(vv[0], vv[1]), vv[2]);
            float e0 = __expf(vv[0] - mx), e1 = __expf(vv[1] - mx), e2 = __expf(vv[2] - mx);
            float rs = __builtin_amdgcn_rcpf(e0 + e1 + e2);
            vv[0] = e0 * rs; vv[1] = e1 * rs; vv[2] = e2 * rs;
        }

        // ---- E: store own 16-col out slice; impute x(t+1) locally into LDS+regs ----
        if (hm == (s >> 1)) {
            int gp = (s & 1) * 2;
            size_t ob0 = ((size_t)t * 2048 + row0 + c) * 128 + hm * 32 + 4 * lh;
            f32x4 o0 = {vv[4 * gp], vv[4 * gp + 1], vv[4 * gp + 2], vv[4 * gp + 3]};
            f32x4 o1 = {vv[4 * gp + 4], vv[4 * gp + 5], vv[4 * gp + 6], vv[4 * gp + 7]};
            *reinterpret_cast<f32x4*>(out + ob0 + 8 * gp) = o0;
            *reinterpret_cast<f32x4*>(out + ob0 + 8 * gp + 8) = o1;
        }
        if (t < TSTEPS - 1) {
#pragma unroll
            for (int g = 0; g < 4; ++g) {
                unsigned int w0 = 0, w1 = 0;
#pragma unroll
                for (int j = 0; j < 4; ++j) {
                    float sqv = sq[g][j];
                    float xf = (sqv != sqv) ? vv[4 * g + j] : sqv;   // isnan -> model output
                    unsigned short nv = f2bf(xf);
                    if (j < 2) w0 |= (unsigned)nv << (16 * j);
                    else       w1 |= (unsigned)nv << (16 * (j - 2));
                }
                xv[2 * g] = w0; xv[2 * g + 1] = w1;
                u32x2 wp = {w0, w1};
                *reinterpret_cast<u32x2*>(&xh[ht][c][hm * 32 + 8 * g + 4 * lh]) = wp;
            }
        }
        HBAR();                                // x(t+1) visible before next gates
    }
#undef HBAR
}

// ---------------------------------------------------------------------------
extern "C" void kernel_launch(void* const* d_in, const int* in_sizes, int n_in,
                              void* d_out, int out_size, void* d_ws, size_t ws_size,
                              hipStream_t stream) {
    const float* seq  = (const float*)d_in[0];
    const float* Wih  = (const float*)d_in[1];
    const float* Whh  = (const float*)d_in[2];
    const float* bih  = (const float*)d_in[3];
    const float* bhh  = (const float*)d_in[4];
    const float* Wcat = (const float*)d_in[5];
    const float* bcat = (const float*)d_in[6];
    const float* Wval = (const float*)d_in[7];
    const float* bval = (const float*)d_in[8];

    char* ws = (char*)d_ws;
    unsigned short* Wg    = (unsigned short*)(ws);                 //  786432 B
    unsigned short* Wo    = (unsigned short*)(ws + 786432);        //   65536 B
    float*          bgp   = (float*)(ws + 851968);                 //    4096 B
    float*          bop   = (float*)(ws + 856064);                 //     512 B
    unsigned int*   flags = (unsigned int*)(ws + 856576);          //    4096 B
    unsigned short* hbuf  = (unsigned short*)(ws + 860672);        // 2097152 B (2 parity buffers)
    // total ws use: 2957824 B

    prep_kernel<<<1673, 256, 0, stream>>>(Wih, Whh, bih, bhh, Wcat, bcat, Wval, bval,
                                          Wg, Wo, bgp, bop, flags);
    rnn_kernel<<<256, 512, 32768, stream>>>(seq, Wg, Wo, bgp, bop, hbuf, flags, (float*)d_out);
}

// Round 7
// 1267.722 us; speedup vs baseline: 1.1778x; 1.1329x over previous
//
#include <hip/hip_runtime.h>
#include <hip/hip_bf16.h>

// Sizes: T=256, B=2048, NC=3, NM=125, IN=128, H=256, 4H=1024, K_gates=384
// 256 WGs x 512 thr, 1 WG/CU. bid = s*32 + r  (s = h-col slice 0..7, r = row block
// 0..31) -> bid%8 = r%8 -> the 8 slice-WGs of a group share an XCD (L2 locality).
// TRANSPOSED GEMMs (32x32x16), all weights persistent in VGPR A-frags (R3 skeleton).
// Exchange redesign (this round):
//  - per-slice flags: producer publishes flag[r][s]=t+1 with a plain sc0/sc1 store
//    after a syncthreads (no atomic RMW, no leader poll-serialization).
//  - per-wave restage: wave w polls flag[r][w] then restages slice w (slice-major
//    hb layout, fully coalesced). Early slices load while stragglers publish.
//  - own-slice LDS shortcut: each wave ds-writes its own h piece directly into xh
//    after barrier1; wave s skips the LLC round trip entirely.
//  - 3 barriers/step (was 4), zero atomics.
constexpr int TSTEPS = 255;
constexpr int XROW   = 392;   // LDS x|h row stride (shorts): [x 0..127 | h 128..383] + 8 pad

typedef __attribute__((ext_vector_type(8))) short short8;
typedef __attribute__((ext_vector_type(4))) float f32x4;
typedef __attribute__((ext_vector_type(16))) float f32x16;
typedef __attribute__((ext_vector_type(4))) int i32x4;
typedef __attribute__((ext_vector_type(2))) unsigned int u32x2;

__device__ __forceinline__ unsigned short f2bf(float f) {
    __hip_bfloat16 h = __float2bfloat16(f);
    return *reinterpret_cast<unsigned short*>(&h);
}
__device__ __forceinline__ float bf2f(unsigned short u) {
    __hip_bfloat16 h;
    *reinterpret_cast<unsigned short*>(&h) = u;
    return __bfloat162float(h);
}
__device__ __forceinline__ float sigf(float x) {
    return __builtin_amdgcn_rcpf(1.f + __expf(-x));
}
__device__ __forceinline__ float tanh_fast(float x) {
    x = fminf(fmaxf(x, -15.f), 15.f);
    float e = __expf(-2.f * x);
    return (1.f - e) * __builtin_amdgcn_rcpf(1.f + e);
}

// Coherent (cross-XCD) accesses: sc0 sc1 bypass non-coherent caches.
__device__ __forceinline__ i32x4 load_coh16(const void* p) {
    i32x4 r;
    asm volatile("global_load_dwordx4 %0, %1, off sc0 sc1" : "=v"(r) : "v"(p) : "memory");
    return r;
}
__device__ __forceinline__ void store_coh16(void* p, i32x4 v) {
    asm volatile("global_store_dwordx4 %0, %1, off sc0 sc1" :: "v"(p), "v"(v) : "memory");
}
__device__ __forceinline__ void store_coh_u32(unsigned int* p, unsigned int v) {
    asm volatile("global_store_dword %0, %1, off sc0 sc1" :: "v"(p), "v"(v) : "memory");
}
__device__ __forceinline__ unsigned int load_coh_u32(const unsigned int* p) {
    unsigned int r;
    asm volatile("global_load_dword %0, %1, off sc0 sc1\n\ts_waitcnt vmcnt(0)"
                 : "=v"(r) : "v"(p) : "memory");
    return r;
}

// ---------------------------------------------------------------------------
// Prep: pack weights to bf16 MFMA A-fragment order; fuse biases; zero flags.
// Gate pack (393216, 32x32x16 A-frags): idx = (((s*4+gm)*24+kt)*64+l)*8+j
//   pm = l&31; n = (pm&3)*256 + s*32 + gm*8 + (pm>>2); k = kt*16 + (l>>5)*8 + j
// Out pack (32768, 32x32x16 A-frags): idx = ((om*16+kt)*64+l)*8+j
//   oc = om*32 + (l&31); k = kt*16 + (l>>5)*8 + j
// ---------------------------------------------------------------------------
__global__ void prep_kernel(const float* __restrict__ Wih, const float* __restrict__ Whh,
                            const float* __restrict__ bih, const float* __restrict__ bhh,
                            const float* __restrict__ Wcat, const float* __restrict__ bcat,
                            const float* __restrict__ Wval, const float* __restrict__ bval,
                            unsigned short* __restrict__ Wg, unsigned short* __restrict__ Wo,
                            float* __restrict__ bg, float* __restrict__ bo,
                            unsigned int* __restrict__ flags) {
    int idx = blockIdx.x * 256 + threadIdx.x;
    if (idx < 393216) {
        int j   = idx & 7;
        int l   = (idx >> 3) & 63;
        int t24 = idx >> 9;
        int kt  = t24 % 24;
        int u   = t24 / 24;            // s*4 + gm
        int gm = u & 3, ss = u >> 2;
        int pm = l & 31;
        int n  = (pm & 3) * 256 + ss * 32 + gm * 8 + (pm >> 2);
        int k  = kt * 16 + (l >> 5) * 8 + j;
        float v = (k < 128) ? Wih[n * 128 + k] : Whh[n * 256 + (k - 128)];
        Wg[idx] = f2bf(v);
    } else if (idx < 425984) {
        int i2 = idx - 393216;
        int j = i2 & 7, ll = (i2 >> 3) & 63, kt = (i2 >> 9) & 15, om = i2 >> 13;
        int n = om * 32 + (ll & 31);
        int k = kt * 16 + (ll >> 5) * 8 + j;
        float v = (n < 3) ? Wcat[n * 256 + k] : Wval[(n - 3) * 256 + k];
        Wo[i2] = f2bf(v);
    } else if (idx < 427008) {
        int i3 = idx - 425984;
        bg[i3] = bih[i3] + bhh[i3];
    } else if (idx < 427136) {
        int i4 = idx - 427008;
        bo[i4] = (i4 < 3) ? bcat[i4] : bval[i4 - 3];
    } else if (idx < 428160) {
        flags[idx - 427136] = 0u;      // per-slice flags (re-zeroed every launch/replay)
    }
}

// ---------------------------------------------------------------------------
// Main persistent kernel: grid=256, 512 threads, 1 WG/CU (84 KB LDS).
// hb layout (slice-major, per parity 1 MB): [r(32)][s(8)][R(64)][64B].
// flag layout: flags[(r*8 + s)*4]  (16B-spaced u32), value = steps published.
// ---------------------------------------------------------------------------
__global__ __launch_bounds__(512, 2) void rnn_kernel(
    const float* __restrict__ seq,
    const unsigned short* __restrict__ Wg, const unsigned short* __restrict__ Wo,
    const float* __restrict__ bg, const float* __restrict__ bo,
    unsigned short* __restrict__ hb, unsigned int* __restrict__ flags,
    float* __restrict__ out) {

    __shared__ __align__(16) unsigned short xh[64][XROW];   // 50176 B: [x(128)|h(256)]
    __shared__ __align__(16) float bgl[128];                // permuted gate bias
    __shared__ __align__(16) float obl[128];                // permuted out bias
    extern __shared__ char lds_pad[];                       // +32768 B -> 1 WG/CU
    (void)lds_pad;

    const int tid = threadIdx.x;
    const int wv  = tid >> 6, l = tid & 63;
    const int c   = l & 31, lh = l >> 5;
    const int s   = blockIdx.x >> 5;       // col slice 0..7
    const int r   = blockIdx.x & 31;       // row block 0..31 (group; same XCD via %8)
    const int row0 = r * 64;
    const int hm  = wv >> 1;               // m-tile within role (gate/out col tile)
    const int bn  = wv & 1;                // row half
    const int R   = bn * 32 + c;           // local batch row 0..63
    const bool hm0lh0 = (hm == 0) && (lh == 0);

    unsigned int* flagOwn = flags + (size_t)(r * 8 + s) * 4;
    unsigned int* flagW   = flags + (size_t)(r * 8 + wv) * 4;

    // ---- persistent weight A-fragments in VGPRs ----
    short8 wga[24], woa[16];
    {
        const short8* WgV = reinterpret_cast<const short8*>(Wg);
        const short8* WoV = reinterpret_cast<const short8*>(Wo);
#pragma unroll
        for (int kt = 0; kt < 24; ++kt) wga[kt] = WgV[(size_t)(((s * 4 + hm) * 24 + kt) * 64) + l];
#pragma unroll
        for (int kt = 0; kt < 16; ++kt) woa[kt] = WoV[(size_t)((hm * 16 + kt) * 64) + l];
    }

    // ---- permuted biases -> LDS ----
    if (tid < 128) {
        int gm_ = tid >> 5, lh_ = (tid >> 4) & 1, i_ = tid & 15;
        int pm = (i_ & 3) + 8 * (i_ >> 2) + 4 * lh_;
        bgl[tid] = bg[(pm & 3) * 256 + s * 32 + gm_ * 8 + (pm >> 2)];
        obl[tid] = bo[gm_ * 32 + 8 * (i_ >> 2) + 4 * lh_ + (i_ & 3)];
    }

    // ---- x(0) = bf16(seq[0]) (NaN-free), h(0) = 0 ----
#pragma unroll
    for (int i = 0; i < 4; ++i) {
        int ch = i * 512 + tid;
        int row = ch >> 5, c4 = ch & 31;
        f32x4 v = *reinterpret_cast<const f32x4*>(seq + (size_t)(row0 + row) * 128 + c4 * 4);
        unsigned short* p = &xh[row][c4 * 4];
        p[0] = f2bf(v[0]); p[1] = f2bf(v[1]); p[2] = f2bf(v[2]); p[3] = f2bf(v[3]);
    }
    {
        short8 z = {0, 0, 0, 0, 0, 0, 0, 0};
#pragma unroll
        for (int i = 0; i < 4; ++i) {
            int ch = i * 512 + tid;
            *reinterpret_cast<short8*>(&xh[ch >> 5][128 + (ch & 31) * 8]) = z;
        }
    }

    // ---- reg-resident bf16 x(t) at lane's 16 cols (row R, base hm*32+4lh) ----
    unsigned int xv[8];
    {
        const float* sp0 = seq + (size_t)(row0 + R) * 128 + hm * 32 + 4 * lh;
#pragma unroll
        for (int g = 0; g < 4; ++g) {
            f32x4 v = *reinterpret_cast<const f32x4*>(sp0 + 8 * g);
            xv[2 * g]     = (unsigned)f2bf(v[0]) | ((unsigned)f2bf(v[1]) << 16);
            xv[2 * g + 1] = (unsigned)f2bf(v[2]) | ((unsigned)f2bf(v[3]) << 16);
        }
    }

    float cst[4] = {0.f, 0.f, 0.f, 0.f};
    const float* bgp = &bgl[(hm * 2 + lh) * 16];
    const float* obp = &obl[(hm * 2 + lh) * 16];
    const unsigned short* xrow = &xh[R][0];

    __syncthreads();

    for (int t = 0; t < TSTEPS; ++t) {
        // ---- prefetch seq[t+1] (consumed in phase E) ----
        f32x4 sq[4];
        if (t < TSTEPS - 1) {
            const float* sp = seq + ((size_t)(t + 1) * 2048 + row0 + R) * 128 + hm * 32 + 4 * lh;
#pragma unroll
            for (int g = 0; g < 4; ++g) sq[g] = *reinterpret_cast<const f32x4*>(sp + 8 * g);
        }

        // ---- A: gates^T = Wg.[x|h]^T + b  (24 MFMA / wave, 2-way acc chain) ----
        f32x16 acc, accB;
#pragma unroll
        for (int i = 0; i < 16; ++i) { acc[i] = bgp[i]; accB[i] = 0.f; }
        __builtin_amdgcn_s_setprio(1);
#pragma unroll
        for (int kt = 0; kt < 24; kt += 2) {
            short8 b0 = *reinterpret_cast<const short8*>(xrow + kt * 16 + lh * 8);
            short8 b1 = *reinterpret_cast<const short8*>(xrow + (kt + 1) * 16 + lh * 8);
            acc  = __builtin_amdgcn_mfma_f32_32x32x16_bf16(wga[kt], b0, acc, 0, 0, 0);
            accB = __builtin_amdgcn_mfma_f32_32x32x16_bf16(wga[kt + 1], b1, accB, 0, 0, 0);
        }
        __builtin_amdgcn_s_setprio(0);
#pragma unroll
        for (int i = 0; i < 16; ++i) acc[i] += accB[i];

        // ---- B: LSTM (in-lane); pack pairs across lh; coherent h-slice store ----
        float hn[4];
#pragma unroll
        for (int g = 0; g < 4; ++g) {
            float cn = sigf(acc[4 * g + 1]) * cst[g] + sigf(acc[4 * g]) * tanh_fast(acc[4 * g + 2]);
            hn[g] = sigf(acc[4 * g + 3]) * tanh_fast(cn);
            cst[g] = cn;
        }
        {
            i32x4 hw;
#pragma unroll
            for (int g = 0; g < 4; ++g) {
                float other = __shfl_xor(hn[g], 32);
                unsigned short lo = f2bf(lh ? other : hn[g]);
                unsigned short hi = f2bf(lh ? hn[g] : other);
                hw[g] = (int)((unsigned)lo | ((unsigned)hi << 16));
            }
            if (lh == 0) {
                // slice-major: [r][s][R][64B]; this wave's 16B at col-offset hm*16
                char* hp = (char*)hb + (size_t)(t & 1) * 1048576 + (size_t)r * 32768
                         + (size_t)s * 4096 + (size_t)R * 64 + hm * 16;
                store_coh16(hp, hw);
            }
        }
        asm volatile("s_waitcnt vmcnt(0)" ::: "memory");
        __syncthreads();                   // barrier1: all coherent stores drained

        // ---- publish flag; own-slice LDS shortcut; per-wave slice restage ----
        if (tid == 0) store_coh_u32(flagOwn, (unsigned)(t + 1));
        {
            // own slice: write this wave's h piece straight into xh (no LLC trip)
#pragma unroll
            for (int g = 0; g < 4; ++g)
                xh[R][128 + s * 32 + hm * 8 + 2 * g + lh] = f2bf(hn[g]);
        }
        if (wv != s) {
            // wave wv restages slice wv: poll its flag, then coalesced 64B/lane
            unsigned int fv;
            do {
                fv = load_coh_u32(flagW);
                if (fv >= (unsigned)(t + 1)) break;
                __builtin_amdgcn_s_sleep(2);
            } while (true);
            const char* hsrc = (const char*)hb + (size_t)(t & 1) * 1048576
                             + (size_t)r * 32768 + (size_t)wv * 4096 + (size_t)l * 64;
            i32x4 hv[4];
#pragma unroll
            for (int q = 0; q < 4; ++q) hv[q] = load_coh16(hsrc + q * 16);
            asm volatile("s_waitcnt vmcnt(0)" ::: "memory");
            __builtin_amdgcn_sched_barrier(0);
#pragma unroll
            for (int q = 0; q < 4; ++q)
                *reinterpret_cast<i32x4*>(&xh[l][128 + wv * 32 + q * 8]) = hv[q];
        }
        __syncthreads();                   // barrier2: h(t+1) fully staged in LDS

        // ---- C: out^T = Wo.h^T + b  (16 MFMA / wave, 2-way acc chain) ----
        f32x16 acc2, acc2B;
#pragma unroll
        for (int i = 0; i < 16; ++i) { acc2[i] = obp[i]; acc2B[i] = 0.f; }
        __builtin_amdgcn_s_setprio(1);
#pragma unroll
        for (int kt = 0; kt < 16; kt += 2) {
            short8 b0 = *reinterpret_cast<const short8*>(xrow + 128 + kt * 16 + lh * 8);
            short8 b1 = *reinterpret_cast<const short8*>(xrow + 128 + (kt + 1) * 16 + lh * 8);
            acc2  = __builtin_amdgcn_mfma_f32_32x32x16_bf16(woa[kt], b0, acc2, 0, 0, 0);
            acc2B = __builtin_amdgcn_mfma_f32_32x32x16_bf16(woa[kt + 1], b1, acc2B, 0, 0, 0);
        }
        __builtin_amdgcn_s_setprio(0);

        // ---- D: + i_val (reg-resident), in-lane softmax over cols 0..2 ----
        float vv[16];
#pragma unroll
        for (int g = 0; g < 4; ++g) {
#pragma unroll
            for (int j = 0; j < 4; ++j) {
                int i = 4 * g + j;
                float v = acc2[i] + acc2B[i];
                unsigned short x16 = (unsigned short)(xv[2 * g + (j >> 1)] >> ((j & 1) * 16));
                bool isCat = (g == 0) && (j < 3) && hm0lh0;
                if (!isCat) v += bf2f(x16);
                vv[i] = v;
            }
        }
        if (hm0lh0) {
            float mx = fmaxf(fmaxf(vv[0], vv[1]), vv[2]);
            float e0 = __expf(vv[0] - mx), e1 = __expf(vv[1] - mx), e2 = __expf(vv[2] - mx);
            float rs = __builtin_amdgcn_rcpf(e0 + e1 + e2);
            vv[0] = e0 * rs; vv[1] = e1 * rs; vv[2] = e2 * rs;
        }

        // ---- E: store own 16-col out slice; impute x(t+1) into LDS + regs ----
        if (hm == (s >> 1)) {
            int gp = (s & 1) * 2;
            size_t ob0 = ((size_t)t * 2048 + row0 + R) * 128 + hm * 32 + 4 * lh;
            f32x4 o0 = {vv[4 * gp], vv[4 * gp + 1], vv[4 * gp + 2], vv[4 * gp + 3]};
            f32x4 o1 = {vv[4 * gp + 4], vv[4 * gp + 5], vv[4 * gp + 6], vv[4 * gp + 7]};
            *reinterpret_cast<f32x4*>(out + ob0 + 8 * gp) = o0;
            *reinterpret_cast<f32x4*>(out + ob0 + 8 * gp + 8) = o1;
        }
        if (t < TSTEPS - 1) {
#pragma unroll
            for (int g = 0; g < 4; ++g) {
                unsigned int w0 = 0, w1 = 0;
#pragma unroll
                for (int j = 0; j < 4; ++j) {
                    float sqv = sq[g][j];
                    float xf = (sqv != sqv) ? vv[4 * g + j] : sqv;   // isnan -> model output
                    unsigned short nv = f2bf(xf);
                    if (j < 2) w0 |= (unsigned)nv << (16 * j);
                    else       w1 |= (unsigned)nv << (16 * (j - 2));
                }
                xv[2 * g] = w0; xv[2 * g + 1] = w1;
                u32x2 wp = {w0, w1};
                *reinterpret_cast<u32x2*>(&xh[R][hm * 32 + 8 * g + 4 * lh]) = wp;
            }
        }
        __syncthreads();                   // barrier3: x(t+1)/h visible for next gates
    }
}

// ---------------------------------------------------------------------------
extern "C" void kernel_launch(void* const* d_in, const int* in_sizes, int n_in,
                              void* d_out, int out_size, void* d_ws, size_t ws_size,
                              hipStream_t stream) {
    const float* seq  = (const float*)d_in[0];
    const float* Wih  = (const float*)d_in[1];
    const float* Whh  = (const float*)d_in[2];
    const float* bih  = (const float*)d_in[3];
    const float* bhh  = (const float*)d_in[4];
    const float* Wcat = (const float*)d_in[5];
    const float* bcat = (const float*)d_in[6];
    const float* Wval = (const float*)d_in[7];
    const float* bval = (const float*)d_in[8];

    char* ws = (char*)d_ws;
    unsigned short* Wg    = (unsigned short*)(ws);                 //  786432 B
    unsigned short* Wo    = (unsigned short*)(ws + 786432);        //   65536 B
    float*          bgp   = (float*)(ws + 851968);                 //    4096 B
    float*          bop   = (float*)(ws + 856064);                 //     512 B
    unsigned int*   flags = (unsigned int*)(ws + 856576);          //    4096 B
    unsigned short* hbuf  = (unsigned short*)(ws + 860672);        // 2097152 B (2 parity buffers)
    // total ws use: 2957824 B

    prep_kernel<<<1673, 256, 0, stream>>>(Wih, Whh, bih, bhh, Wcat, bcat, Wval, bval,
                                          Wg, Wo, bgp, bop, flags);
    rnn_kernel<<<256, 512, 32768, stream>>>(seq, Wg, Wo, bgp, bop, hbuf, flags, (float*)d_out);
}

// Round 9
// 1144.985 us; speedup vs baseline: 1.3041x; 1.1072x over previous
//
#include <hip/hip_runtime.h>
#include <hip/hip_bf16.h>

// Sizes: T=256, B=2048, NC=3, NM=125, IN=128, H=256, 4H=1024, K_gates=384
// 256 WGs x 512 thr. WG = (s = h-col slice 0..7, r = row block 0..31), rows [64r, 64r+64).
// TRANSPOSED GEMMs: gates^T = Wg.[x|h]^T, out^T = Wo.h^T  (32x32x16 MFMA).
//  - ALL weights live in VGPRs as A-fragments (gate slice: 24 frags = 96 VGPR,
//    out-proj full 128 cols: 16 frags = 64 VGPR). Zero weight traffic per step.
//  - B-fragments = x|h rows, contiguous ds_read_b128 from LDS.
//  - D: lane = one batch row x 16 packed cols (LSTM register-local; in-lane softmax,
//    reg-resident i_val, dwordx4 stores, b64 impute writes).
//  - per step: ONLY h exchanged among the 8 slice-WGs of a row block (sc0/sc1
//    coherent accesses + one relaxed agent-scope flag barrier, parity dbuf).
// This round (vs verified-1123 R3 baseline): 2-way MFMA accumulator split in both
// GEMMs (halve serial MFMA latency chain) + s_setprio around MFMA clusters.
// Exchange structure deliberately untouched (R4-R8 alternatives all regressed).
constexpr int TSTEPS = 255;
constexpr int XROW   = 392;   // LDS x|h row stride (shorts): [x 0..127 | h 128..383] + 8 pad

typedef __attribute__((ext_vector_type(8))) short short8;
typedef __attribute__((ext_vector_type(4))) float f32x4;
typedef __attribute__((ext_vector_type(16))) float f32x16;
typedef __attribute__((ext_vector_type(4))) int i32x4;
typedef __attribute__((ext_vector_type(2))) unsigned int u32x2;

__device__ __forceinline__ unsigned short f2bf(float f) {
    __hip_bfloat16 h = __float2bfloat16(f);
    return *reinterpret_cast<unsigned short*>(&h);
}
__device__ __forceinline__ float bf2f(unsigned short u) {
    __hip_bfloat16 h;
    *reinterpret_cast<unsigned short*>(&h) = u;
    return __bfloat162float(h);
}
__device__ __forceinline__ float sigf(float x) {
    return __builtin_amdgcn_rcpf(1.f + __expf(-x));
}
__device__ __forceinline__ float tanh_fast(float x) {
    x = fminf(fmaxf(x, -15.f), 15.f);
    float e = __expf(-2.f * x);
    return (1.f - e) * __builtin_amdgcn_rcpf(1.f + e);
}

// Coherent (cross-XCD) accesses: sc0 sc1 bypass non-coherent caches.
__device__ __forceinline__ i32x4 load_coh16(const void* p) {
    i32x4 r;
    asm volatile("global_load_dwordx4 %0, %1, off sc0 sc1" : "=v"(r) : "v"(p) : "memory");
    return r;
}
__device__ __forceinline__ void store_coh16(void* p, i32x4 v) {
    asm volatile("global_store_dwordx4 %0, %1, off sc0 sc1" :: "v"(p), "v"(v) : "memory");
}

// 8-WG group barrier: vmcnt drain (covers inline-asm coherent stores) -> syncthreads
// -> leader relaxed agent-scope add + poll -> syncthreads.
__device__ __forceinline__ void groupbar(unsigned int* cnt, unsigned int tgt, int tid) {
    asm volatile("s_waitcnt vmcnt(0)" ::: "memory");
    __syncthreads();
    if (tid == 0) {
        __hip_atomic_fetch_add(cnt, 1u, __ATOMIC_RELAXED, __HIP_MEMORY_SCOPE_AGENT);
        while (__hip_atomic_load(cnt, __ATOMIC_RELAXED, __HIP_MEMORY_SCOPE_AGENT) < tgt)
            __builtin_amdgcn_s_sleep(1);
    }
    __syncthreads();
}

// ---------------------------------------------------------------------------
// Prep: pack weights to bf16 MFMA A-fragment order; fuse biases; zero flags.
// Gate pack (393216, 32x32x16 A-frags): idx = (((s*4+gm)*24+kt)*64+l)*8+j
//   pm = l&31; n = (pm&3)*256 + s*32 + gm*8 + (pm>>2); k = kt*16 + (l>>5)*8 + j
// Out pack (32768, 32x32x16 A-frags): idx = ((om*16+kt)*64+l)*8+j
//   oc = om*32 + (l&31); k = kt*16 + (l>>5)*8 + j
// ---------------------------------------------------------------------------
__global__ void prep_kernel(const float* __restrict__ Wih, const float* __restrict__ Whh,
                            const float* __restrict__ bih, const float* __restrict__ bhh,
                            const float* __restrict__ Wcat, const float* __restrict__ bcat,
                            const float* __restrict__ Wval, const float* __restrict__ bval,
                            unsigned short* __restrict__ Wg, unsigned short* __restrict__ Wo,
                            float* __restrict__ bg, float* __restrict__ bo,
                            unsigned int* __restrict__ flags) {
    int idx = blockIdx.x * 256 + threadIdx.x;
    if (idx < 393216) {
        int j   = idx & 7;
        int l   = (idx >> 3) & 63;
        int t24 = idx >> 9;
        int kt  = t24 % 24;
        int u   = t24 / 24;            // s*4 + gm
        int gm = u & 3, ss = u >> 2;
        int pm = l & 31;
        int n  = (pm & 3) * 256 + ss * 32 + gm * 8 + (pm >> 2);
        int k  = kt * 16 + (l >> 5) * 8 + j;
        float v = (k < 128) ? Wih[n * 128 + k] : Whh[n * 256 + (k - 128)];
        Wg[idx] = f2bf(v);
    } else if (idx < 425984) {
        int i2 = idx - 393216;
        int j = i2 & 7, ll = (i2 >> 3) & 63, kt = (i2 >> 9) & 15, om = i2 >> 13;
        int n = om * 32 + (ll & 31);
        int k = kt * 16 + (ll >> 5) * 8 + j;
        float v = (n < 3) ? Wcat[n * 256 + k] : Wval[(n - 3) * 256 + k];
        Wo[i2] = f2bf(v);
    } else if (idx < 427008) {
        int i3 = idx - 425984;
        bg[i3] = bih[i3] + bhh[i3];
    } else if (idx < 427136) {
        int i4 = idx - 427008;
        bo[i4] = (i4 < 3) ? bcat[i4] : bval[i4 - 3];
    } else if (idx < 428160) {
        flags[idx - 427136] = 0u;      // barrier counters (re-zeroed every launch/replay)
    }
}

// ---------------------------------------------------------------------------
// Main persistent kernel: grid=256, 512 threads, 1 WG/CU (84 KB LDS).
// ---------------------------------------------------------------------------
__global__ __launch_bounds__(512, 2) void rnn_kernel(
    const float* __restrict__ seq,
    const unsigned short* __restrict__ Wg, const unsigned short* __restrict__ Wo,
    const float* __restrict__ bg, const float* __restrict__ bo,
    unsigned short* __restrict__ hb, unsigned int* __restrict__ flags,
    float* __restrict__ out) {

    __shared__ __align__(16) unsigned short xh[64][XROW];   // 50176 B: [x(128) | h(256)] per row
    __shared__ __align__(16) float bgl[128];                // permuted gate bias
    __shared__ __align__(16) float obl[128];                // permuted out bias
    extern __shared__ char lds_pad[];                       // +32768 B at launch -> 1 WG/CU
    (void)lds_pad;

    const int tid = threadIdx.x;
    const int wv  = tid >> 6, l = tid & 63;
    const int c   = l & 31, lh = l >> 5;
    const int s   = blockIdx.x >> 5;       // col slice 0..7
    const int r   = blockIdx.x & 31;       // row block 0..31
    const int row0 = r * 64;
    const int hm  = wv >> 1;               // m-tile: gm for gates, om for out-proj
    const int bn  = wv & 1;                // row half
    const int R   = bn * 32 + c;           // local batch row 0..63
    const bool hm0lh0 = (hm == 0) && (lh == 0);

    unsigned int* cnt = flags + r * 16;

    // ---- persistent weight A-fragments in VGPRs ----
    short8 wga[24], woa[16];
    {
        const short8* WgV = reinterpret_cast<const short8*>(Wg);
        const short8* WoV = reinterpret_cast<const short8*>(Wo);
#pragma unroll
        for (int kt = 0; kt < 24; ++kt) wga[kt] = WgV[(size_t)(((s * 4 + hm) * 24 + kt) * 64) + l];
#pragma unroll
        for (int kt = 0; kt < 16; ++kt) woa[kt] = WoV[(size_t)((hm * 16 + kt) * 64) + l];
    }

    // ---- permuted biases -> LDS (per-lane-class contiguous, broadcast reads) ----
    if (tid < 128) {
        int gm_ = tid >> 5, lh_ = (tid >> 4) & 1, i_ = tid & 15;
        int pm = (i_ & 3) + 8 * (i_ >> 2) + 4 * lh_;
        bgl[tid] = bg[(pm & 3) * 256 + s * 32 + gm_ * 8 + (pm >> 2)];
        obl[tid] = bo[gm_ * 32 + 8 * (i_ >> 2) + 4 * lh_ + (i_ & 3)];
    }

    // ---- x(0) = bf16(seq[0]) (NaN-free), h(0) = 0 ----
#pragma unroll
    for (int i = 0; i < 4; ++i) {
        int ch = i * 512 + tid;
        int row = ch >> 5, c4 = ch & 31;
        f32x4 v = *reinterpret_cast<const f32x4*>(seq + (size_t)(row0 + row) * 128 + c4 * 4);
        unsigned short* p = &xh[row][c4 * 4];
        p[0] = f2bf(v[0]); p[1] = f2bf(v[1]); p[2] = f2bf(v[2]); p[3] = f2bf(v[3]);
    }
    {
        short8 z = {0, 0, 0, 0, 0, 0, 0, 0};
#pragma unroll
        for (int i = 0; i < 4; ++i) {
            int ch = i * 512 + tid;
            int row = ch >> 5, k8 = ch & 31;
            *reinterpret_cast<short8*>(&xh[row][128 + k8 * 8]) = z;
        }
    }

    // ---- xv = reg-resident bf16 x(t) at lane's 16 cols (base hm*32+8g'+4lh) ----
    unsigned int xv[8];
    {
        const float* sp0 = seq + (size_t)(row0 + R) * 128 + hm * 32 + 4 * lh;
#pragma unroll
        for (int g = 0; g < 4; ++g) {
            f32x4 v = *reinterpret_cast<const f32x4*>(sp0 + 8 * g);
            xv[2 * g]     = (unsigned int)f2bf(v[0]) | ((unsigned int)f2bf(v[1]) << 16);
            xv[2 * g + 1] = (unsigned int)f2bf(v[2]) | ((unsigned int)f2bf(v[3]) << 16);
        }
    }

    float cst[4] = {0.f, 0.f, 0.f, 0.f};
    const float* bgp = &bgl[(hm * 2 + lh) * 16];
    const float* obp = &obl[(hm * 2 + lh) * 16];
    const unsigned short* xrow = &xh[R][0];

    __syncthreads();

    for (int t = 0; t < TSTEPS; ++t) {
        // ---- prefetch seq[t+1] (consumed after the barrier; hides HBM latency) ----
        f32x4 sq[4];
        if (t < TSTEPS - 1) {
            const float* sp = seq + ((size_t)(t + 1) * 2048 + row0 + R) * 128 + hm * 32 + 4 * lh;
#pragma unroll
            for (int g = 0; g < 4; ++g) sq[g] = *reinterpret_cast<const f32x4*>(sp + 8 * g);
        }

        // ---- A: gates^T = Wg.[x|h]^T + b  (24 MFMA / wave, 2-way acc chain) ----
        f32x16 acc, accB;
#pragma unroll
        for (int i = 0; i < 16; ++i) { acc[i] = bgp[i]; accB[i] = 0.f; }
        __builtin_amdgcn_s_setprio(1);
#pragma unroll
        for (int kt = 0; kt < 24; kt += 2) {
            short8 b0 = *reinterpret_cast<const short8*>(xrow + kt * 16 + lh * 8);
            short8 b1 = *reinterpret_cast<const short8*>(xrow + (kt + 1) * 16 + lh * 8);
            acc  = __builtin_amdgcn_mfma_f32_32x32x16_bf16(wga[kt], b0, acc, 0, 0, 0);
            accB = __builtin_amdgcn_mfma_f32_32x32x16_bf16(wga[kt + 1], b1, accB, 0, 0, 0);
        }
        __builtin_amdgcn_s_setprio(0);
#pragma unroll
        for (int i = 0; i < 16; ++i) acc[i] += accB[i];

        // ---- B: LSTM (in-lane: acc[4g'+{0,1,2,3}] = i,f,g,o of h-col gm*8+2g'+lh) ----
        float hn[4];
#pragma unroll
        for (int g = 0; g < 4; ++g) {
            float cn = sigf(acc[4 * g + 1]) * cst[g] + sigf(acc[4 * g]) * tanh_fast(acc[4 * g + 2]);
            hn[g] = sigf(acc[4 * g + 3]) * tanh_fast(cn);
            cst[g] = cn;
        }
        // pack pairs across lh halves -> cols [s*32+hm*8, +8) of row R, one dwordx4
        {
            i32x4 hw;
#pragma unroll
            for (int g = 0; g < 4; ++g) {
                float other = __shfl_xor(hn[g], 32);
                unsigned short lo = f2bf(lh ? other : hn[g]);
                unsigned short hi = f2bf(lh ? hn[g] : other);
                hw[g] = (int)((unsigned int)lo | ((unsigned int)hi << 16));
            }
            if (lh == 0) {
                char* hp = (char*)hb + (size_t)(t & 1) * 1048576 + (size_t)r * 32768
                         + (size_t)R * 512 + s * 64 + hm * 16;
                store_coh16(hp, hw);
            }
        }

        groupbar(cnt, 8u * (t + 1), tid);      // all 8 slices published h(t+1)

        // ---- restage full h(t+1) row-block: coherent 16B loads -> LDS ----
        {
            const unsigned short* hsrc = hb + (size_t)(t & 1) * 524288 + (size_t)r * 16384;
            i32x4 hv[4];
#pragma unroll
            for (int i = 0; i < 4; ++i) {
                int ch = i * 512 + tid;        // Rl = ch>>5, c16 = ch&31
                hv[i] = load_coh16(hsrc + (size_t)((ch >> 5) * 256 + (ch & 31) * 8));
            }
            asm volatile("s_waitcnt vmcnt(0)" ::: "memory");
            __builtin_amdgcn_sched_barrier(0);
#pragma unroll
            for (int i = 0; i < 4; ++i) {
                int ch = i * 512 + tid;
                *reinterpret_cast<i32x4*>(&xh[ch >> 5][128 + (ch & 31) * 8]) = hv[i];
            }
        }
        __syncthreads();

        // ---- C: out^T = Wo.h^T + b  (16 MFMA / wave, 2-way acc chain) ----
        f32x16 acc2, acc2B;
#pragma unroll
        for (int i = 0; i < 16; ++i) { acc2[i] = obp[i]; acc2B[i] = 0.f; }
        __builtin_amdgcn_s_setprio(1);
#pragma unroll
        for (int kt = 0; kt < 16; kt += 2) {
            short8 b0 = *reinterpret_cast<const short8*>(xrow + 128 + kt * 16 + lh * 8);
            short8 b1 = *reinterpret_cast<const short8*>(xrow + 128 + (kt + 1) * 16 + lh * 8);
            acc2  = __builtin_amdgcn_mfma_f32_32x32x16_bf16(woa[kt], b0, acc2, 0, 0, 0);
            acc2B = __builtin_amdgcn_mfma_f32_32x32x16_bf16(woa[kt + 1], b1, acc2B, 0, 0, 0);
        }
        __builtin_amdgcn_s_setprio(0);

        // ---- D: + i_val (reg-resident), in-lane softmax over cols 0..2 ----
        float vv[16];
#pragma unroll
        for (int g = 0; g < 4; ++g) {
#pragma unroll
            for (int j = 0; j < 4; ++j) {
                int i = 4 * g + j;
                float v = acc2[i] + acc2B[i];
                unsigned short x16 = (unsigned short)(xv[2 * g + (j >> 1)] >> ((j & 1) * 16));
                bool isCat = (g == 0) && (j < 3) && hm0lh0;
                if (!isCat) v += bf2f(x16);
                vv[i] = v;
            }
        }
        if (hm0lh0) {
            float mx = fmaxf(fmaxf(vv[0], vv[1]), vv[2]);
            float e0 = __expf(vv[0] - mx), e1 = __expf(vv[1] - mx), e2 = __expf(vv[2] - mx);
            float rs = __builtin_amdgcn_rcpf(e0 + e1 + e2);
            vv[0] = e0 * rs; vv[1] = e1 * rs; vv[2] = e2 * rs;
        }

        // ---- E: store own out slice (cols [16s,16s+16)); impute x(t+1) locally ----
        if (hm == (s >> 1)) {
            int gp = (s & 1) * 2;
            size_t ob0 = ((size_t)t * 2048 + row0 + R) * 128 + hm * 32 + 4 * lh;
            f32x4 o0 = {vv[4 * gp], vv[4 * gp + 1], vv[4 * gp + 2], vv[4 * gp + 3]};
            f32x4 o1 = {vv[4 * gp + 4], vv[4 * gp + 5], vv[4 * gp + 6], vv[4 * gp + 7]};
            *reinterpret_cast<f32x4*>(out + ob0 + 8 * gp) = o0;
            *reinterpret_cast<f32x4*>(out + ob0 + 8 * gp + 8) = o1;
        }
        if (t < TSTEPS - 1) {
#pragma unroll
            for (int g = 0; g < 4; ++g) {
                unsigned int w0 = 0, w1 = 0;
#pragma unroll
                for (int j = 0; j < 4; ++j) {
                    unsigned short s16 = f2bf(sq[g][j]);
                    bool nan = (s16 & 0x7fff) > 0x7f80;
                    unsigned short nv = nan ? f2bf(vv[4 * g + j]) : s16;
                    if (j < 2) w0 |= (unsigned int)nv << (16 * j);
                    else       w1 |= (unsigned int)nv << (16 * (j - 2));
                }
                xv[2 * g] = w0; xv[2 * g + 1] = w1;
                u32x2 wp = {w0, w1};
                *reinterpret_cast<u32x2*>(&xh[R][hm * 32 + 8 * g + 4 * lh]) = wp;
            }
        }
        __syncthreads();
    }
}

// ---------------------------------------------------------------------------
extern "C" void kernel_launch(void* const* d_in, const int* in_sizes, int n_in,
                              void* d_out, int out_size, void* d_ws, size_t ws_size,
                              hipStream_t stream) {
    const float* seq  = (const float*)d_in[0];
    const float* Wih  = (const float*)d_in[1];
    const float* Whh  = (const float*)d_in[2];
    const float* bih  = (const float*)d_in[3];
    const float* bhh  = (const float*)d_in[4];
    const float* Wcat = (const float*)d_in[5];
    const float* bcat = (const float*)d_in[6];
    const float* Wval = (const float*)d_in[7];
    const float* bval = (const float*)d_in[8];

    char* ws = (char*)d_ws;
    unsigned short* Wg    = (unsigned short*)(ws);                 //  786432 B
    unsigned short* Wo    = (unsigned short*)(ws + 786432);        //   65536 B
    float*          bgp   = (float*)(ws + 851968);                 //    4096 B
    float*          bop   = (float*)(ws + 856064);                 //     512 B
    unsigned int*   flags = (unsigned int*)(ws + 856576);          //    4096 B
    unsigned short* hbuf  = (unsigned short*)(ws + 860672);        // 2097152 B (2 parity buffers)
    // total ws use: 2957824 B

    prep_kernel<<<1673, 256, 0, stream>>>(Wih, Whh, bih, bhh, Wcat, bcat, Wval, bval,
                                          Wg, Wo, bgp, bop, flags);
    rnn_kernel<<<256, 512, 32768, stream>>>(seq, Wg, Wo, bgp, bop, hbuf, flags, (float*)d_out);
}